// Round 7
// baseline (498.909 us; speedup 1.0000x reference)
//
#include <hip/hip_runtime.h>

#define NTOK 16384
#define DIM  128
#define NJT  128   // number of 128-wide j tiles
#define RB   64    // i-rows per attn block

typedef __attribute__((ext_vector_type(8))) short short8;
typedef __attribute__((ext_vector_type(4))) float f32x4;
typedef __attribute__((ext_vector_type(4))) int   i32x4;
typedef __attribute__((address_space(1))) void void_g;
typedef __attribute__((address_space(3))) void void_l;

// fold 1/sqrt(128) * log2(e) into Q so scores come out in log2 domain
#define QSCALE (1.4426950408889634f * 0.08838834764831845f)

#define VMCNT(n) asm volatile("s_waitcnt vmcnt(" #n ")" ::: "memory")
#define FENCE()  asm volatile("" ::: "memory")

__device__ __forceinline__ short f2bf(float f) {
  union { float f; unsigned u; } v; v.f = f;
  return (short)((v.u + 0x7FFFu + ((v.u >> 16) & 1u)) >> 16);
}

// packed f32x2 -> bf16x2 (RNE), single VALU op
__device__ __forceinline__ unsigned pkbf(float lo, float hi) {
  unsigned r;
  asm("v_cvt_pk_bf16_f32 %0, %1, %2" : "=v"(r) : "v"(lo), "v"(hi));
  return r;
}

__device__ __forceinline__ short8 pack8(const float4 a, const float4 b) {
  short8 r;
  r[0] = f2bf(a.x); r[1] = f2bf(a.y); r[2] = f2bf(a.z); r[3] = f2bf(a.w);
  r[4] = f2bf(b.x); r[5] = f2bf(b.y); r[6] = f2bf(b.z); r[7] = f2bf(b.w);
  return r;
}

__device__ __forceinline__ void gload16(char* l, const char* g) {
  __builtin_amdgcn_global_load_lds((void_g*)g, (void_l*)l, 16, 0, 0);
}

// V2 chunk offset: chunk (t, kf, lg, d) is 16 bytes
__device__ __forceinline__ int kvoff(int t, int kf, int lg, int r) {
  return ((((t * 4 + kf) * 4 + lg) * 128) + r) * 16;
}

// ---------------------------------------------------------------------------
// Kernel 1: QKV projection (unchanged from round 5).
// ---------------------------------------------------------------------------
__device__ __forceinline__ void mm16(const short8 (&af)[4], const float* __restrict__ W,
                                     const float* __restrict__ b, int l15, int lg,
                                     f32x4 (&acc)[8], float (&bias)[8]) {
#pragma unroll
  for (int nf = 0; nf < 8; ++nf) {
    acc[nf][0] = 0.f; acc[nf][1] = 0.f; acc[nf][2] = 0.f; acc[nf][3] = 0.f;
  }
#pragma unroll
  for (int kf = 0; kf < 4; ++kf) {
#pragma unroll
    for (int nf = 0; nf < 8; ++nf) {
      const float* wp = W + (size_t)(nf * 16 + l15) * DIM + kf * 32 + lg * 8;
      short8 bfr = pack8(*(const float4*)wp, *(const float4*)(wp + 4));
      acc[nf] = __builtin_amdgcn_mfma_f32_16x16x32_bf16(af[kf], bfr, acc[nf], 0, 0, 0);
    }
  }
#pragma unroll
  for (int nf = 0; nf < 8; ++nf) bias[nf] = b[nf * 16 + l15];
}

__global__ __launch_bounds__(256) void proj_kernel(
    const float* __restrict__ X,
    const float* __restrict__ Wq, const float* __restrict__ bq,
    const float* __restrict__ Wk, const float* __restrict__ bk,
    const float* __restrict__ Wv, const float* __restrict__ bv,
    short* __restrict__ Qb, char* __restrict__ K3, char* __restrict__ V2) {
  __shared__ short ktile[64][136];
  __shared__ short vtile[64][136];

  const int tid = threadIdx.x;
  const int w = tid >> 6, lane = tid & 63;
  const int l15 = lane & 15, lg = lane >> 4;
  const int i0 = blockIdx.x * 64;
  const int t = i0 >> 7, jl0 = i0 & 127;

  short8 af[4];
  {
    const int xrow = i0 + w * 16 + l15;
#pragma unroll
    for (int kf = 0; kf < 4; ++kf) {
      const float* xp = X + (size_t)xrow * DIM + kf * 32 + lg * 8;
      af[kf] = pack8(*(const float4*)xp, *(const float4*)(xp + 4));
    }
  }

  f32x4 acc[8];
  float bias[8];

  // ---- Q ----
  mm16(af, Wq, bq, l15, lg, acc, bias);
#pragma unroll
  for (int nf = 0; nf < 8; ++nf) {
    const int d = nf * 16 + l15;
#pragma unroll
    for (int rr = 0; rr < 4; ++rr) {
      const int i = i0 + w * 16 + lg * 4 + rr;
      Qb[(size_t)i * DIM + d] = f2bf((acc[nf][rr] + bias[nf]) * QSCALE);
    }
  }

  // ---- K ----
  mm16(af, Wk, bk, l15, lg, acc, bias);
#pragma unroll
  for (int nf = 0; nf < 8; ++nf) {
    const int d = nf * 16 + l15;
#pragma unroll
    for (int rr = 0; rr < 4; ++rr)
      ktile[w * 16 + lg * 4 + rr][d] = f2bf(acc[nf][rr] + bias[nf]);
  }

  // ---- V ----
  mm16(af, Wv, bv, l15, lg, acc, bias);
#pragma unroll
  for (int nf = 0; nf < 8; ++nf) {
    const int d = nf * 16 + l15;
#pragma unroll
    for (int rr = 0; rr < 4; ++rr)
      vtile[w * 16 + lg * 4 + rr][d] = f2bf(acc[nf][rr] + bias[nf]);
  }
  __syncthreads();

  // K3 chunks
#pragma unroll
  for (int it = 0; it < 4; ++it) {
    const int task = it * 256 + tid;
    const int o = task >> 6, jr = task & 63;
    const int j = i0 + jr;
    const int jfg = (j >> 4) & 7;
    const int kf = o >> 2, lgc = o & 3;
    short8 st = *(const short8*)&ktile[jr][o * 8];
    *(short8*)(K3 + ((size_t)((t * 8 + jfg) * 4 + kf) << 10) + lgc * 256 + (j & 15) * 16) = st;
  }

  // V2 chunks
#pragma unroll
  for (int it = 0; it < 4; ++it) {
    const int task = it * 256 + tid;
    const int c = task >> 7, d = task & 127;
    short8 st;
#pragma unroll
    for (int s2 = 0; s2 < 8; ++s2) st[s2] = vtile[c * 8 + s2][d];
    const int jl = jl0 + c * 8;
    const int kf = jl >> 5, lg2 = (jl >> 3) & 3;
    *(short8*)(V2 + kvoff(t, kf, lg2, d)) = st;
  }
}

// ---------------------------------------------------------------------------
// Kernel 2: fused masked-softmax attention, counted-vmcnt pipeline.
// 256 blocks x 1024 threads (16 waves, 4 waves/SIMD at <=128 VGPR).
// Wave (ir, wc): i-rows [ir*16,+16), j-slice [wc*32,+32).
// K double-buffered in LDS (32KB/step staged, stage(t+1) in flight across
// the barrier); V + adj register-buffered from L2/HBM. Per-step VMEM order:
// [adj 2][stage 2][ ... ][vfr 8]; waits: vmcnt(8) at top, vmcnt(4) pre-PV.
// ---------------------------------------------------------------------------
__device__ __forceinline__ void stage_k(char* dst, const char* __restrict__ K3,
                                        int t, int tid) {
  const char* gk = K3 + ((size_t)t << 15);
  const int o = tid * 16;
  gload16(dst + o,         gk + o);
  gload16(dst + 16384 + o, gk + 16384 + o);
}

__device__ __forceinline__ void load_adj(i32x4 (&a)[2], const int* __restrict__ adj,
                                         int t, int i0, int ir, int wc, int l15, int lg) {
  const int* ap = adj + (size_t)(i0 + ir * 16 + l15) * NTOK + t * 128 + wc * 32 + lg * 4;
  a[0] = *(const i32x4*)ap;
  a[1] = *(const i32x4*)(ap + 16);
}

__device__ __forceinline__ void load_v(short8 (&v)[8], const char* __restrict__ V2,
                                       int t, int wc, int l15, int lg) {
#pragma unroll
  for (int nf = 0; nf < 8; ++nf)
    v[nf] = *(const short8*)(V2 + kvoff(t, wc, lg, nf * 16 + l15));
}

__device__ __forceinline__ void attn_step(
    int t, const char* cur, char* nxt,
    const char* __restrict__ K3, const char* __restrict__ V2,
    const int* __restrict__ adj,
    const short8 (&qf)[4], short8 (&vfr)[8], f32x4 (&acc)[8], float& dsum,
    const i32x4 (&adjC)[2], i32x4 (&adjN)[2],
    int i0, int ir, int wc, int l15, int lg, int lane, int tid,
    int adA, int adB, bool hi5) {
  const int tn = (t + 1) & (NJT - 1);

  // top-of-step: stage(t) + adj(t) landed (8 newest outstanding = vfr(t));
  // raw barrier (NO vmcnt0 drain) -- stage(t+1)/vfr stay in flight after it
  VMCNT(8);
  __builtin_amdgcn_s_barrier();

  load_adj(adjN, adj, tn, i0, ir, wc, l15, lg);   // 2 VMEM
  FENCE();
  stage_k(nxt, K3, tn, tid);                      // 2 VMEM
  FENCE();

  // ---- S^T = K @ Q^T : lane holds S[i=l15][j=(wc*2+jf)*16 + lg*4+r] ----
  f32x4 sT[2];
#pragma unroll
  for (int jf = 0; jf < 2; ++jf) {
    sT[jf][0] = 0.f; sT[jf][1] = 0.f; sT[jf][2] = 0.f; sT[jf][3] = 0.f;
  }
#pragma unroll
  for (int jf = 0; jf < 2; ++jf)
#pragma unroll
    for (int kf = 0; kf < 4; ++kf) {
      const short8 kfr = *(const short8*)(cur + (((wc * 2 + jf) * 4 + kf) << 10) + lane * 16);
      sT[jf] = __builtin_amdgcn_mfma_f32_16x16x32_bf16(kfr, qf[kf], sT[jf], 0, 0, 0);
    }

  // ---- mask + exp2 + row-sum + pack, all in-register (adjC ready) ----
  unsigned pk_[2][2];
#pragma unroll
  for (int jf = 0; jf < 2; ++jf) {
    const i32x4 a = adjC[jf];
    const float p0 = __builtin_exp2f(a[0] ? sT[jf][0] : 0.0f);
    const float p1 = __builtin_exp2f(a[1] ? sT[jf][1] : 0.0f);
    const float p2 = __builtin_exp2f(a[2] ? sT[jf][2] : 0.0f);
    const float p3 = __builtin_exp2f(a[3] ? sT[jf][3] : 0.0f);
    dsum += (p0 + p1) + (p2 + p3);
    pk_[jf][0] = pkbf(p0, p1);
    pk_[jf][1] = pkbf(p2, p3);
  }

  // ---- in-wave exchange: build PV A-frag P[i=l15][j=lg*8+e] ----
  i32x4 pa;
#pragma unroll
  for (int w2 = 0; w2 < 4; ++w2) {
    const int addr = (w2 < 2) ? adA : adB;
    const int r0 = __builtin_amdgcn_ds_bpermute(addr, (int)pk_[0][w2 & 1]);
    const int r1 = __builtin_amdgcn_ds_bpermute(addr, (int)pk_[1][w2 & 1]);
    pa[w2] = hi5 ? r1 : r0;
  }
  const short8 pa8 = *(const short8*)&pa;

  // vfr(t) landed (outstanding <=4 = adj(t+1) 2 + stage(t+1) 2)
  VMCNT(4);

  // ---- acc += P @ V (this wave's j:32, full d:128) ----
#pragma unroll
  for (int nf = 0; nf < 8; ++nf)
    acc[nf] = __builtin_amdgcn_mfma_f32_16x16x32_bf16(pa8, vfr[nf], acc[nf], 0, 0, 0);

  FENCE();
  load_v(vfr, V2, tn, wc, l15, lg);               // 8 VMEM (for t+1)
  FENCE();
}

__global__ __launch_bounds__(1024, 4) void attn_kernel(
    const short* __restrict__ QbG, const char* __restrict__ K3,
    const char* __restrict__ V2, const int* __restrict__ adj,
    float* __restrict__ out) {
  __shared__ __align__(16) char kbuf[2][32768];   // K double buffer
  __shared__ float denp[4][64];

  const int tid = threadIdx.x;
  const int w = tid >> 6, lane = tid & 63;
  const int l15 = lane & 15, lg = lane >> 4;
  const int ir = w >> 2, wc = w & 3;
  const int i0 = blockIdx.x * RB;

  const int adA = 4 * (l15 + 16 * ((lg & 1) * 2));
  const int adB = adA + 64;
  const bool hi5 = (lane & 32) != 0;

  // Q B-frags (persist): lane holds Q[i = i0+ir*16+l15][kf*32+lg*8 ..+8]
  short8 qf[4];
  {
    const int i = i0 + ir * 16 + l15;
#pragma unroll
    for (int kf = 0; kf < 4; ++kf)
      qf[kf] = *(const short8*)(QbG + (size_t)i * DIM + kf * 32 + lg * 8);
  }

  f32x4 acc[8];
#pragma unroll
  for (int nf = 0; nf < 8; ++nf) {
    acc[nf][0] = 0.f; acc[nf][1] = 0.f; acc[nf][2] = 0.f; acc[nf][3] = 0.f;
  }
  float dsum = 0.f;
  i32x4 adjA_[2], adjB_[2];
  short8 vfr[8];

  // prologue: [qf 4][stage(0) 2][adj(0) 2][vfr(0) 8] -> loop-top vmcnt(8) OK
  FENCE();
  stage_k(kbuf[0], K3, 0, tid);
  FENCE();
  load_adj(adjA_, adj, 0, i0, ir, wc, l15, lg);
  FENCE();
  load_v(vfr, V2, 0, wc, l15, lg);
  FENCE();

  for (int t = 0; t < NJT; t += 2) {
    attn_step(t,     kbuf[0], kbuf[1], K3, V2, adj, qf, vfr, acc, dsum,
              adjA_, adjB_, i0, ir, wc, l15, lg, lane, tid, adA, adB, hi5);
    attn_step(t + 1, kbuf[1], kbuf[0], K3, V2, adj, qf, vfr, acc, dsum,
              adjB_, adjA_, i0, ir, wc, l15, lg, lane, tid, adA, adB, hi5);
  }

  // drain all in-flight VMEM (incl. other-purpose DMA into kbuf) before reuse
  VMCNT(0);

  // ---- denominator: lane covers i=l15; sum over lg groups, then wc ----
  float d0 = dsum;
  d0 += __shfl_xor(d0, 16);
  d0 += __shfl_xor(d0, 32);
  if (lg == 0) denp[wc][ir * 16 + l15] = d0;

  // ---- cross-wc acc reduction through LDS (reuse kbuf: 33.8KB/round) ----
  float* red = (float*)kbuf;   // 4 slots x 16 rows x 132 floats
#pragma unroll
  for (int rnd = 1; rnd <= 3; ++rnd) {
    __syncthreads();
    if (wc == rnd) {
      const int base = ir * 16 * 132;
#pragma unroll
      for (int nf = 0; nf < 8; ++nf)
#pragma unroll
        for (int r = 0; r < 4; ++r)
          red[base + (lg * 4 + r) * 132 + nf * 16 + l15] = acc[nf][r];
    }
    __syncthreads();
    if (wc == 0) {
      const int base = ir * 16 * 132;
#pragma unroll
      for (int nf = 0; nf < 8; ++nf)
#pragma unroll
        for (int r = 0; r < 4; ++r)
          acc[nf][r] += red[base + (lg * 4 + r) * 132 + nf * 16 + l15];
    }
  }

  if (wc == 0) {
    float den[4];
#pragma unroll
    for (int r = 0; r < 4; ++r) {
      const int il = ir * 16 + lg * 4 + r;
      den[r] = (denp[0][il] + denp[1][il]) + (denp[2][il] + denp[3][il]);
    }
#pragma unroll
    for (int nf = 0; nf < 8; ++nf)
#pragma unroll
      for (int r = 0; r < 4; ++r) {
        const int i = ir * 16 + lg * 4 + r;
        out[(size_t)(i0 + i) * DIM + nf * 16 + l15] = acc[nf][r] / den[r];
      }
  }
}

// ---------------------------------------------------------------------------
extern "C" void kernel_launch(void* const* d_in, const int* in_sizes, int n_in,
                              void* d_out, int out_size, void* d_ws, size_t ws_size,
                              hipStream_t stream) {
  const float* X  = (const float*)d_in[0];
  const float* Wq = (const float*)d_in[1];
  const float* bq = (const float*)d_in[2];
  const float* Wk = (const float*)d_in[3];
  const float* bk = (const float*)d_in[4];
  const float* Wv = (const float*)d_in[5];
  const float* bv = (const float*)d_in[6];
  const int*  adj = (const int*)d_in[7];
  float* out = (float*)d_out;

  char* ws = (char*)d_ws;
  short* Qb = (short*)ws;                       // 4 MB bf16 [N][128]
  char*  K3 = ws + ((size_t)4 << 20);           // 4 MB A-frag-contiguous K
  char*  V2 = ws + ((size_t)8 << 20);           // 4 MB B-frag-contiguous V^T

  proj_kernel<<<256, 256, 0, stream>>>(X, Wq, bq, Wk, bk, Wv, bv, Qb, K3, V2);
  attn_kernel<<<256, 1024, 0, stream>>>(Qb, K3, V2, adj, out);
}

// Round 8
// 349.675 us; speedup vs baseline: 1.4268x; 1.4268x over previous
//
#include <hip/hip_runtime.h>

#define NTOK 16384
#define DIM  128
#define NJT  128   // number of 128-wide j tiles
#define RB   64    // i-rows per attn block

typedef __attribute__((ext_vector_type(8))) short short8;
typedef __attribute__((ext_vector_type(4))) float f32x4;
typedef __attribute__((ext_vector_type(4))) int   i32x4;
typedef __attribute__((address_space(1))) void void_g;
typedef __attribute__((address_space(3))) void void_l;

// fold 1/sqrt(128) * log2(e) into Q so scores come out in log2 domain
#define QSCALE (1.4426950408889634f * 0.08838834764831845f)

__device__ __forceinline__ short f2bf(float f) {
  union { float f; unsigned u; } v; v.f = f;
  return (short)((v.u + 0x7FFFu + ((v.u >> 16) & 1u)) >> 16);
}

// packed f32x2 -> bf16x2, single VALU op (dst.lo = bf16(a), dst.hi = bf16(b))
__device__ __forceinline__ unsigned pkbf2(float a, float b) {
  unsigned r;
  asm("v_cvt_pk_bf16_f32 %0, %1, %2" : "=v"(r) : "v"(a), "v"(b));
  return r;
}

__device__ __forceinline__ short8 pack8(const float4 a, const float4 b) {
  union { unsigned u[4]; short8 s; } r;
  r.u[0] = pkbf2(a.x, a.y);
  r.u[1] = pkbf2(a.z, a.w);
  r.u[2] = pkbf2(b.x, b.y);
  r.u[3] = pkbf2(b.z, b.w);
  return r.s;
}

__device__ __forceinline__ void gload16(char* l, const char* g) {
  __builtin_amdgcn_global_load_lds((void_g*)g, (void_l*)l, 16, 0, 0);
}

__device__ __forceinline__ float bf2f(short s) {
  union { float f; unsigned u; } v;
  v.u = ((unsigned)(unsigned short)s) << 16;
  return v.f;
}

// ---------------------------------------------------------------------------
// Kernel 1: QKV projection.
//  Qb: [N][128] bf16 row-major, pre-scaled by QSCALE
//  K3 (bf16): A-frag chunks, tile t = 32KB; chunk(jfg,kf)=1KB; lane l holds
//      K[t*128 + jfg*16 + (l&15)][kf*32 + (l>>4)*8 .. +8] at lane*16
//  V8 (fp8 e4m3): tile t = 16KB; chunk(jg,d) = 8B = V[t*128+jg*8 .. +8][d]
// ---------------------------------------------------------------------------
__device__ __forceinline__ void mm16(const short8 (&af)[4], const float* __restrict__ W,
                                     const float* __restrict__ b, int l15, int lg,
                                     f32x4 (&acc)[8], float (&bias)[8]) {
#pragma unroll
  for (int nf = 0; nf < 8; ++nf) {
    acc[nf][0] = 0.f; acc[nf][1] = 0.f; acc[nf][2] = 0.f; acc[nf][3] = 0.f;
  }
#pragma unroll
  for (int kf = 0; kf < 4; ++kf) {
#pragma unroll
    for (int nf = 0; nf < 8; ++nf) {
      const float* wp = W + (size_t)(nf * 16 + l15) * DIM + kf * 32 + lg * 8;
      short8 bfr = pack8(*(const float4*)wp, *(const float4*)(wp + 4));
      acc[nf] = __builtin_amdgcn_mfma_f32_16x16x32_bf16(af[kf], bfr, acc[nf], 0, 0, 0);
    }
  }
#pragma unroll
  for (int nf = 0; nf < 8; ++nf) bias[nf] = b[nf * 16 + l15];
}

__global__ __launch_bounds__(256) void proj_kernel(
    const float* __restrict__ X,
    const float* __restrict__ Wq, const float* __restrict__ bq,
    const float* __restrict__ Wk, const float* __restrict__ bk,
    const float* __restrict__ Wv, const float* __restrict__ bv,
    short* __restrict__ Qb, char* __restrict__ K3, char* __restrict__ V8) {
  __shared__ short ktile[64][136];
  __shared__ short vtile[64][136];

  const int tid = threadIdx.x;
  const int w = tid >> 6, lane = tid & 63;
  const int l15 = lane & 15, lg = lane >> 4;
  const int i0 = blockIdx.x * 64;
  const int t = i0 >> 7, jl0 = i0 & 127;

  short8 af[4];
  {
    const int xrow = i0 + w * 16 + l15;
#pragma unroll
    for (int kf = 0; kf < 4; ++kf) {
      const float* xp = X + (size_t)xrow * DIM + kf * 32 + lg * 8;
      af[kf] = pack8(*(const float4*)xp, *(const float4*)(xp + 4));
    }
  }

  f32x4 acc[8];
  float bias[8];

  // ---- Q ----
  mm16(af, Wq, bq, l15, lg, acc, bias);
#pragma unroll
  for (int nf = 0; nf < 8; ++nf) {
    const int d = nf * 16 + l15;
#pragma unroll
    for (int rr = 0; rr < 4; ++rr) {
      const int i = i0 + w * 16 + lg * 4 + rr;
      Qb[(size_t)i * DIM + d] = f2bf((acc[nf][rr] + bias[nf]) * QSCALE);
    }
  }

  // ---- K ----
  mm16(af, Wk, bk, l15, lg, acc, bias);
#pragma unroll
  for (int nf = 0; nf < 8; ++nf) {
    const int d = nf * 16 + l15;
#pragma unroll
    for (int rr = 0; rr < 4; ++rr)
      ktile[w * 16 + lg * 4 + rr][d] = f2bf(acc[nf][rr] + bias[nf]);
  }

  // ---- V ----
  mm16(af, Wv, bv, l15, lg, acc, bias);
#pragma unroll
  for (int nf = 0; nf < 8; ++nf) {
    const int d = nf * 16 + l15;
#pragma unroll
    for (int rr = 0; rr < 4; ++rr)
      vtile[w * 16 + lg * 4 + rr][d] = f2bf(acc[nf][rr] + bias[nf]);
  }
  __syncthreads();

  // K3 chunks (bf16): task = chunk o (0..15) x local row (0..63)
#pragma unroll
  for (int it = 0; it < 4; ++it) {
    const int task = it * 256 + tid;
    const int o = task >> 6, jr = task & 63;
    const int j = i0 + jr;
    const int jfg = (j >> 4) & 7;
    const int kf = o >> 2, lgc = o & 3;
    short8 st = *(const short8*)&ktile[jr][o * 8];
    *(short8*)(K3 + ((size_t)((t * 8 + jfg) * 4 + kf) << 10) + lgc * 256 + (j & 15) * 16) = st;
  }

  // V8 chunks (fp8): task = c (8 j-octets) x d (128)
#pragma unroll
  for (int it = 0; it < 4; ++it) {
    const int task = it * 256 + tid;
    const int c = task >> 7, d = task & 127;
    float f[8];
#pragma unroll
    for (int s2 = 0; s2 < 8; ++s2) f[s2] = bf2f(vtile[c * 8 + s2][d]);
    int lo = __builtin_amdgcn_cvt_pk_fp8_f32(f[0], f[1], 0, false);
    lo = __builtin_amdgcn_cvt_pk_fp8_f32(f[2], f[3], lo, true);
    int hi = __builtin_amdgcn_cvt_pk_fp8_f32(f[4], f[5], 0, false);
    hi = __builtin_amdgcn_cvt_pk_fp8_f32(f[6], f[7], hi, true);
    const int jg = (jl0 >> 3) + c;   // j-octet index within tile (0..15)
    *(int2*)(V8 + (((size_t)t * 16 + jg) * 128 + d) * 8) = make_int2(lo, hi);
  }
}

// ---------------------------------------------------------------------------
// Kernel 2: fused masked-softmax attention (R5 skeleton + fp8 PV path).
// 256 blocks x 1024 threads (16 waves, 4 waves/SIMD at <=128 VGPR).
// Wave (ir, wc): i-rows [ir*16,+16), j-slice [wc*32,+32).
// K (bf16) + V (fp8) double-buffered in LDS via global_load_lds; one
// __syncthreads per step; softmax in-register (swapped QK^T + bpermute).
// ---------------------------------------------------------------------------
__device__ __forceinline__ void stage_kv(char* kdst, char* vdst,
                                         const char* __restrict__ K3,
                                         const char* __restrict__ V8,
                                         int t, int tid) {
  const char* gk = K3 + ((size_t)t << 15);
  const char* gv = V8 + ((size_t)t << 14);
  const int o = tid * 16;
  gload16(kdst + o,         gk + o);
  gload16(kdst + 16384 + o, gk + 16384 + o);
  gload16(vdst + o,         gv + o);
}

__device__ __forceinline__ void load_adj(i32x4 (&a)[2], const int* __restrict__ adj,
                                         int t, int i0, int ir, int wc, int l15, int lg) {
  const int* ap = adj + (size_t)(i0 + ir * 16 + l15) * NTOK + t * 128 + wc * 32 + lg * 4;
  a[0] = *(const i32x4*)ap;
  a[1] = *(const i32x4*)(ap + 16);
}

__device__ __forceinline__ void attn_step(
    int t, const char* kcur, const char* vcur, char* knxt, char* vnxt,
    const char* __restrict__ K3, const char* __restrict__ V8,
    const int* __restrict__ adj,
    const short8 (&qf)[4], f32x4 (&acc)[8], float& dsum,
    const i32x4 (&adjC)[2], i32x4 (&adjN)[2],
    int i0, int ir, int wc, int l15, int lg, int lane, int tid,
    int ad0, bool selhi) {
  const int tn = (t + 1) & (NJT - 1);

  // stage next K/V tile into the other LDS buffer; prefetch next adj to regs
  stage_kv(knxt, vnxt, K3, V8, tn, tid);
  load_adj(adjN, adj, tn, i0, ir, wc, l15, lg);

  // ---- S^T = K @ Q^T : lane holds S[i=l15][j=(wc*2+jf)*16 + lg*4+r] ----
  f32x4 sT[2];
#pragma unroll
  for (int jf = 0; jf < 2; ++jf) {
    sT[jf][0] = 0.f; sT[jf][1] = 0.f; sT[jf][2] = 0.f; sT[jf][3] = 0.f;
  }
#pragma unroll
  for (int jf = 0; jf < 2; ++jf)
#pragma unroll
    for (int kf = 0; kf < 4; ++kf) {
      const short8 kfr = *(const short8*)(kcur + (((wc * 2 + jf) * 4 + kf) << 10) + lane * 16);
      sT[jf] = __builtin_amdgcn_mfma_f32_16x16x32_bf16(kfr, qf[kf], sT[jf], 0, 0, 0);
    }

  // ---- mask + exp2 (halved) + row-sum + fp8 pack, all in-register ----
  int pk8[2];
#pragma unroll
  for (int jf = 0; jf < 2; ++jf) {
    const i32x4 a = adjC[jf];
    const float p0 = __builtin_exp2f(a[0] ? sT[jf][0] : 0.0f) * 0.5f;
    const float p1 = __builtin_exp2f(a[1] ? sT[jf][1] : 0.0f) * 0.5f;
    const float p2 = __builtin_exp2f(a[2] ? sT[jf][2] : 0.0f) * 0.5f;
    const float p3 = __builtin_exp2f(a[3] ? sT[jf][3] : 0.0f) * 0.5f;
    dsum += (p0 + p1) + (p2 + p3);
    int d0 = __builtin_amdgcn_cvt_pk_fp8_f32(p0, p1, 0, false);
    pk8[jf] = __builtin_amdgcn_cvt_pk_fp8_f32(p2, p3, d0, true);
  }

  // ---- in-wave exchange: build fp8 PV A-frag P[i=l15][j=lg*8+e] ----
  union { int2 i2; long l; } pa;
#pragma unroll
  for (int w2 = 0; w2 < 2; ++w2) {
    const int addr = ad0 + w2 * 64;
    const int r0 = __builtin_amdgcn_ds_bpermute(addr, pk8[0]);
    const int r1 = __builtin_amdgcn_ds_bpermute(addr, pk8[1]);
    (w2 ? pa.i2.y : pa.i2.x) = selhi ? r1 : r0;
  }

  // ---- acc += P @ V (fp8 x fp8, this wave's j:32, full d:128) ----
#pragma unroll
  for (int nf = 0; nf < 8; ++nf) {
    const long vb = *(const long*)(vcur + (((wc * 4 + lg) * 128 + nf * 16 + l15) << 3));
    acc[nf] = __builtin_amdgcn_mfma_f32_16x16x32_fp8_fp8(pa.l, vb, acc[nf], 0, 0, 0);
  }

  // vmcnt(0)+lgkmcnt(0)+barrier: stage complete, buffers flip
  __syncthreads();
}

__global__ __launch_bounds__(1024, 4) void attn_kernel(
    const short* __restrict__ QbG, const char* __restrict__ K3,
    const char* __restrict__ V8, const int* __restrict__ adj,
    float* __restrict__ out) {
  __shared__ __align__(16) char kbuf[2][32768];   // K bf16 double buffer
  __shared__ __align__(16) char vbuf[2][16384];   // V fp8 double buffer
  __shared__ float denp[4][64];

  const int tid = threadIdx.x;
  const int w = tid >> 6, lane = tid & 63;
  const int l15 = lane & 15, lg = lane >> 4;
  const int ir = w >> 2, wc = w & 3;
  const int i0 = blockIdx.x * RB;

  // bpermute source lane for (w2): lg_src = (lg*2 + w2) & 3; select jf by lg>=2
  const int ad0 = 4 * (l15 + 16 * ((lg * 2) & 3));
  const bool selhi = (lg & 2) != 0;

  // Q B-frags (persist): lane holds Q[i = i0+ir*16+l15][kf*32+lg*8 ..+8]
  short8 qf[4];
  {
    const int i = i0 + ir * 16 + l15;
#pragma unroll
    for (int kf = 0; kf < 4; ++kf)
      qf[kf] = *(const short8*)(QbG + (size_t)i * DIM + kf * 32 + lg * 8);
  }

  f32x4 acc[8];
#pragma unroll
  for (int nf = 0; nf < 8; ++nf) {
    acc[nf][0] = 0.f; acc[nf][1] = 0.f; acc[nf][2] = 0.f; acc[nf][3] = 0.f;
  }
  float dsum = 0.f;
  i32x4 adjA_[2], adjB_[2];

  stage_kv(kbuf[0], vbuf[0], K3, V8, 0, tid);
  load_adj(adjA_, adj, 0, i0, ir, wc, l15, lg);
  __syncthreads();

  for (int t = 0; t < NJT; t += 2) {
    attn_step(t,     kbuf[0], vbuf[0], kbuf[1], vbuf[1], K3, V8, adj, qf, acc,
              dsum, adjA_, adjB_, i0, ir, wc, l15, lg, lane, tid, ad0, selhi);
    attn_step(t + 1, kbuf[1], vbuf[1], kbuf[0], vbuf[0], K3, V8, adj, qf, acc,
              dsum, adjB_, adjA_, i0, ir, wc, l15, lg, lane, tid, ad0, selhi);
  }

  // ---- denominator: lane covers i=l15; sum over lg groups, then wc ----
  float d0 = dsum;
  d0 += __shfl_xor(d0, 16);
  d0 += __shfl_xor(d0, 32);
  if (lg == 0) denp[wc][ir * 16 + l15] = d0;

  // ---- cross-wc acc reduction through LDS (reuse kbuf: 33.8KB/round) ----
  float* red = (float*)kbuf;   // 4 slots x 16 rows x 132 floats
#pragma unroll
  for (int rnd = 1; rnd <= 3; ++rnd) {
    __syncthreads();
    if (wc == rnd) {
      const int base = ir * 16 * 132;
#pragma unroll
      for (int nf = 0; nf < 8; ++nf)
#pragma unroll
        for (int r = 0; r < 4; ++r)
          red[base + (lg * 4 + r) * 132 + nf * 16 + l15] = acc[nf][r];
    }
    __syncthreads();
    if (wc == 0) {
      const int base = ir * 16 * 132;
#pragma unroll
      for (int nf = 0; nf < 8; ++nf)
#pragma unroll
        for (int r = 0; r < 4; ++r)
          acc[nf][r] += red[base + (lg * 4 + r) * 132 + nf * 16 + l15];
    }
  }

  if (wc == 0) {
    float den[4];
#pragma unroll
    for (int r = 0; r < 4; ++r) {
      const int il = ir * 16 + lg * 4 + r;
      den[r] = (denp[0][il] + denp[1][il]) + (denp[2][il] + denp[3][il]);
    }
#pragma unroll
    for (int nf = 0; nf < 8; ++nf)
#pragma unroll
      for (int r = 0; r < 4; ++r) {
        const int i = ir * 16 + lg * 4 + r;
        out[(size_t)(i0 + i) * DIM + nf * 16 + l15] = acc[nf][r] / den[r];
      }
  }
}

// ---------------------------------------------------------------------------
extern "C" void kernel_launch(void* const* d_in, const int* in_sizes, int n_in,
                              void* d_out, int out_size, void* d_ws, size_t ws_size,
                              hipStream_t stream) {
  const float* X  = (const float*)d_in[0];
  const float* Wq = (const float*)d_in[1];
  const float* bq = (const float*)d_in[2];
  const float* Wk = (const float*)d_in[3];
  const float* bk = (const float*)d_in[4];
  const float* Wv = (const float*)d_in[5];
  const float* bv = (const float*)d_in[6];
  const int*  adj = (const int*)d_in[7];
  float* out = (float*)d_out;

  char* ws = (char*)d_ws;
  short* Qb = (short*)ws;                       // 4 MB bf16 [N][128]
  char*  K3 = ws + ((size_t)4 << 20);           // 4 MB A-frag-contiguous K (bf16)
  char*  V8 = ws + ((size_t)8 << 20);           // 2 MB fp8 V^T chunks

  proj_kernel<<<256, 256, 0, stream>>>(X, Wq, bq, Wk, bk, Wv, bv, Qb, K3, V8);
  attn_kernel<<<256, 1024, 0, stream>>>(Qb, K3, V8, adj, out);
}